// Round 2
// baseline (788.330 us; speedup 1.0000x reference)
//
#include <hip/hip_runtime.h>
#include <cstdio>

// B=64, NN=17, T=128, H=256.
// d_out = outputs [64,17,128,256] fp32 ++ A [64,17,128,128] fp32.
//
// Refactor: We = Wq^T@Wb@Wk; qWk = node@We; S = qWk@kv^T + b[s]; A = softmax_s(S);
// out = A @ (kv@Wv^T).
// Round 2: QK^T via bf16 MFMA with hi/lo split (3 terms); softmax + PV fused.
// Round 3: V computed inside k_fused (k_vgemm deleted) — but LDS-staged with 40
// barrier rounds -> latency-bound (MfmaUtil 8%, all pipes idle).
// Round 4: V-gemm is now BARRIER-FREE: each wave's A-operand rows (kv rows
// w*32..w*32+31) are wave-private, so fragments are loaded per-lane directly
// from L2-hot kv (no LDS staging, no syncs). vacc for a 128-h half lives in
// 64 VGPRs. LDS only for the V transpose (Vt) before PV. Phase-1 gets a
// register prefetch of next k-step Q/K so its barriers stop exposing global
// latency. Vt writes packed to bf16x4 (ds_write_b64).

typedef __bf16 bf16;
typedef __attribute__((ext_vector_type(8))) __bf16 bf16x8;
typedef __attribute__((ext_vector_type(4))) __bf16 bf16x4;
typedef __attribute__((ext_vector_type(4))) float floatx4;

#define MFMA_BF16 __builtin_amdgcn_mfma_f32_16x16x32_bf16

__device__ __forceinline__ const float* kv_row_ptr(const float* node, const float* neigh, int bn, int s) {
  int b = bn / 17, nn = bn % 17;
  return (nn == 0) ? node + ((size_t)b * 128 + s) * 256
                   : neigh + (((size_t)b * 16 + (nn - 1)) * 128 + s) * 256;
}

// ---------- K0a: Wc = Wq^T @ Wb ----------
__global__ __launch_bounds__(256) void k_wc(const float* __restrict__ Wq, const float* __restrict__ Wb,
                                            float* __restrict__ Wc) {
  int m = blockIdx.x, h = threadIdx.x;
  float acc = 0.f;
  for (int k = 0; k < 256; ++k) acc = fmaf(Wq[k * 256 + m], Wb[k * 256 + h], acc);
  Wc[m * 256 + h] = acc;
}

// ---------- K0b: We = Wc @ Wk ----------
__global__ __launch_bounds__(256) void k_we(const float* __restrict__ Wc, const float* __restrict__ Wk,
                                            float* __restrict__ We) {
  int m = blockIdx.x, g = threadIdx.x;
  float acc = 0.f;
  for (int k = 0; k < 256; ++k) acc = fmaf(Wc[m * 256 + k], Wk[k * 256 + g], acc);
  We[m * 256 + g] = acc;
}

// ---------- K0c: Wvb = bf16(Wv) ----------
__global__ __launch_bounds__(256) void k_wvb(const float* __restrict__ Wv, bf16* __restrict__ Wvb) {
  int i = (blockIdx.x * 256 + threadIdx.x) * 4;
  float4 v = *(const float4*)(Wv + i);
  bf16x4 o;
  o[0] = (bf16)v.x; o[1] = (bf16)v.y; o[2] = (bf16)v.z; o[3] = (bf16)v.w;
  *(bf16x4*)(Wvb + i) = o;
}

// ---------- K1: qWk = node @ We; M=8192,N=256,K=256 fp32 ----------
__global__ __launch_bounds__(256) void k_qwk(const float* __restrict__ X, const float* __restrict__ W,
                                             float* __restrict__ Y) {
  __shared__ float As[32][64];
  __shared__ float Bs[32][64];
  int tid = threadIdx.x;
  int m0 = blockIdx.x * 64, n0 = blockIdx.y * 64;
  int tx = tid & 15, ty = tid >> 4;
  float acc[4][4] = {};
  int r = tid >> 3, c4 = (tid & 7) * 4;
  int kr = tid >> 4, c4b = (tid & 15) * 4;
  for (int k0 = 0; k0 < 256; k0 += 32) {
#pragma unroll
    for (int p = 0; p < 2; ++p) {
      float4 v = *(const float4*)(X + (size_t)(m0 + r + p * 32) * 256 + k0 + c4);
      As[c4 + 0][r + p * 32] = v.x; As[c4 + 1][r + p * 32] = v.y;
      As[c4 + 2][r + p * 32] = v.z; As[c4 + 3][r + p * 32] = v.w;
    }
#pragma unroll
    for (int p = 0; p < 2; ++p) {
      float4 v = *(const float4*)(W + (size_t)(k0 + kr + p * 16) * 256 + n0 + c4b);
      *(float4*)&Bs[kr + p * 16][c4b] = v;
    }
    __syncthreads();
#pragma unroll 8
    for (int k = 0; k < 32; ++k) {
      float a[4], bb[4];
#pragma unroll
      for (int i = 0; i < 4; ++i) a[i] = As[k][ty * 4 + i];
#pragma unroll
      for (int j = 0; j < 4; ++j) bb[j] = Bs[k][tx * 4 + j];
#pragma unroll
      for (int i = 0; i < 4; ++i)
#pragma unroll
        for (int j = 0; j < 4; ++j) acc[i][j] = fmaf(a[i], bb[j], acc[i][j]);
    }
    __syncthreads();
  }
#pragma unroll
  for (int i = 0; i < 4; ++i) {
    float4 v = make_float4(acc[i][0], acc[i][1], acc[i][2], acc[i][3]);
    *(float4*)(Y + (size_t)(m0 + ty * 4 + i) * 256 + n0 + tx * 4) = v;
  }
}

// ---------- K3 fused: S=qWk@kv^T (hi/lo bf16 MFMA) + bias + softmax -> A;
//            barrier-free per-wave V-gemm from L2-hot kv; out = A@V ----------
// one block per bn; 256 threads = 4 waves; wave w owns rows w*32..w*32+31.
#define QKS 40   // padded k-stride (bf16) for Q/K staging buffers
#define ABS 136  // padded s-stride (bf16) for A / Vt buffers
__global__ __launch_bounds__(256) void k_fused(const float* __restrict__ qWk, const float* __restrict__ node,
                                               const float* __restrict__ neigh, const float* __restrict__ bvec,
                                               const bf16* __restrict__ Wvb,
                                               float* __restrict__ Aout, float* __restrict__ Out) {
  __shared__ __align__(16) char smem[52224];
  bf16* Qhi = (bf16*)smem;               // [128][QKS]
  bf16* Qlo = (bf16*)(smem + 10240);
  bf16* Khi = (bf16*)(smem + 20480);
  bf16* Klo = (bf16*)(smem + 30720);
  bf16* Ab  = (bf16*)smem;               // [128][ABS]  (phase 2, aliases Q/K bufs)
  bf16* Vt  = (bf16*)(smem + 34816);     // [64][ABS]   (phase 2)

  int tid = threadIdx.x;
  int w = tid >> 6, lane = tid & 63, lrow = lane & 15, quad = lane >> 4;
  int bn = blockIdx.x;
  const float* Q = qWk + (size_t)(bn / 17) * 128 * 256;
  const float* K = kv_row_ptr(node, neigh, bn, 0);

  int srow = tid >> 1;            // staging row 0..127
  int skb = (tid & 1) * 16;       // staging k base 0 or 16

  floatx4 acc[2][8];
#pragma unroll
  for (int rt = 0; rt < 2; ++rt)
#pragma unroll
    for (int ct = 0; ct < 8; ++ct) acc[rt][ct] = (floatx4)0.0f;

  // ---- phase 1: S = Q @ K^T via 3-term hi/lo split, prefetched staging ----
  const float* qb = Q + (size_t)srow * 256 + skb;
  const float* kb = K + (size_t)srow * 256 + skb;
  float4 pq[4], pk[4];
#pragma unroll
  for (int j = 0; j < 4; ++j) { pq[j] = *(const float4*)(qb + j * 4); pk[j] = *(const float4*)(kb + j * 4); }

  for (int k0 = 0; k0 < 256; k0 += 32) {
#pragma unroll
    for (int half = 0; half < 2; ++half) {
      float qf[8] = {pq[half * 2].x, pq[half * 2].y, pq[half * 2].z, pq[half * 2].w,
                     pq[half * 2 + 1].x, pq[half * 2 + 1].y, pq[half * 2 + 1].z, pq[half * 2 + 1].w};
      float kf[8] = {pk[half * 2].x, pk[half * 2].y, pk[half * 2].z, pk[half * 2].w,
                     pk[half * 2 + 1].x, pk[half * 2 + 1].y, pk[half * 2 + 1].z, pk[half * 2 + 1].w};
      bf16x8 qh, ql, kh, kl;
#pragma unroll
      for (int u = 0; u < 8; ++u) {
        bf16 h = (bf16)qf[u]; qh[u] = h; ql[u] = (bf16)(qf[u] - (float)h);
        bf16 h2 = (bf16)kf[u]; kh[u] = h2; kl[u] = (bf16)(kf[u] - (float)h2);
      }
      int off = srow * QKS + skb + half * 8;
      *(bf16x8*)&Qhi[off] = qh; *(bf16x8*)&Qlo[off] = ql;
      *(bf16x8*)&Khi[off] = kh; *(bf16x8*)&Klo[off] = kl;
    }
    if (k0 < 224) {  // prefetch next k-step; latency spans the barrier + MFMAs
#pragma unroll
      for (int j = 0; j < 4; ++j) {
        pq[j] = *(const float4*)(qb + k0 + 32 + j * 4);
        pk[j] = *(const float4*)(kb + k0 + 32 + j * 4);
      }
    }
    __syncthreads();
    bf16x8 ah[2], al[2];
#pragma unroll
    for (int rt = 0; rt < 2; ++rt) {
      int off = (w * 32 + rt * 16 + lrow) * QKS + quad * 8;
      ah[rt] = *(const bf16x8*)&Qhi[off];
      al[rt] = *(const bf16x8*)&Qlo[off];
    }
#pragma unroll
    for (int ct = 0; ct < 8; ++ct) {
      int off = (ct * 16 + lrow) * QKS + quad * 8;
      bf16x8 bh = *(const bf16x8*)&Khi[off];
      bf16x8 bl = *(const bf16x8*)&Klo[off];
#pragma unroll
      for (int rt = 0; rt < 2; ++rt) {
        acc[rt][ct] = MFMA_BF16(ah[rt], bh, acc[rt][ct], 0, 0, 0);
        acc[rt][ct] = MFMA_BF16(al[rt], bh, acc[rt][ct], 0, 0, 0);
        acc[rt][ct] = MFMA_BF16(ah[rt], bl, acc[rt][ct], 0, 0, 0);
      }
    }
    __syncthreads();
  }

  // ---- softmax over s (per row), in registers ----
  float bvv[8];
#pragma unroll
  for (int ct = 0; ct < 8; ++ct) bvv[ct] = bvec[ct * 16 + lrow];
#pragma unroll
  for (int rt = 0; rt < 2; ++rt)
#pragma unroll
    for (int r = 0; r < 4; ++r) {
      float mx = -3.402823466e+38f;
#pragma unroll
      for (int ct = 0; ct < 8; ++ct) {
        float v = acc[rt][ct][r] + bvv[ct];
        acc[rt][ct][r] = v;
        mx = fmaxf(mx, v);
      }
#pragma unroll
      for (int off = 1; off < 16; off <<= 1) mx = fmaxf(mx, __shfl_xor(mx, off, 64));
      float s = 0.f;
#pragma unroll
      for (int ct = 0; ct < 8; ++ct) {
        float e = __expf(acc[rt][ct][r] - mx);
        acc[rt][ct][r] = e;
        s += e;
      }
#pragma unroll
      for (int off = 1; off < 16; off <<= 1) s += __shfl_xor(s, off, 64);
      float inv = 1.f / s;
#pragma unroll
      for (int ct = 0; ct < 8; ++ct) acc[rt][ct][r] *= inv;
    }

  // ---- write A (global fp32) + Ab (LDS bf16; rows w*32.. are wave-private) ----
  float* Ag = Aout + (size_t)bn * 128 * 128;
#pragma unroll
  for (int rt = 0; rt < 2; ++rt)
#pragma unroll
    for (int r = 0; r < 4; ++r) {
      int row = w * 32 + rt * 16 + quad * 4 + r;
#pragma unroll
      for (int ct = 0; ct < 8; ++ct) {
        int s = ct * 16 + lrow;
        float v = acc[rt][ct][r];
        Ag[(size_t)row * 128 + s] = v;
        Ab[row * ABS + s] = (bf16)v;
      }
    }

  // ---- phase 2: per 128-h half — barrier-free per-wave V-gemm (kv direct
  //      from L2), then per 64-h chunk: Vt transpose + PV ----
  float* Ob = Out + (size_t)bn * 128 * 256;
  for (int hh = 0; hh < 2; ++hh) {
    int H0 = hh * 128;
    floatx4 vacc[2][8];
#pragma unroll
    for (int rt = 0; rt < 2; ++rt)
#pragma unroll
      for (int ct = 0; ct < 8; ++ct) vacc[rt][ct] = (floatx4)0.0f;

#pragma unroll 2
    for (int kk = 0; kk < 8; ++kk) {  // k = kk*32
      bf16x8 af[2];
#pragma unroll
      for (int rt = 0; rt < 2; ++rt) {
        const float* kp = K + (size_t)(w * 32 + rt * 16 + lrow) * 256 + kk * 32 + quad * 8;
        float4 a = *(const float4*)kp, b2 = *(const float4*)(kp + 4);
        bf16x8 o;
        o[0] = (bf16)a.x;  o[1] = (bf16)a.y;  o[2] = (bf16)a.z;  o[3] = (bf16)a.w;
        o[4] = (bf16)b2.x; o[5] = (bf16)b2.y; o[6] = (bf16)b2.z; o[7] = (bf16)b2.w;
        af[rt] = o;
      }
#pragma unroll 4
      for (int ct = 0; ct < 8; ++ct) {
        bf16x8 bwv = *(const bf16x8*)&Wvb[(size_t)(H0 + ct * 16 + lrow) * 256 + kk * 32 + quad * 8];
#pragma unroll
        for (int rt = 0; rt < 2; ++rt)
          vacc[rt][ct] = MFMA_BF16(af[rt], bwv, vacc[rt][ct], 0, 0, 0);
      }
    }

    // two 64-h chunks: transpose V through LDS, then PV
    for (int hc = 0; hc < 2; ++hc) {
#pragma unroll
      for (int ct = 0; ct < 4; ++ct)
#pragma unroll
        for (int rt = 0; rt < 2; ++rt) {
          bf16x4 o;
#pragma unroll
          for (int r = 0; r < 4; ++r) o[r] = (bf16)vacc[rt][hc * 4 + ct][r];
          *(bf16x4*)&Vt[(ct * 16 + lrow) * ABS + w * 32 + rt * 16 + quad * 4] = o;
        }
      __syncthreads();
      floatx4 pacc[2][4];
#pragma unroll
      for (int rt = 0; rt < 2; ++rt)
#pragma unroll
        for (int ct = 0; ct < 4; ++ct) pacc[rt][ct] = (floatx4)0.0f;
#pragma unroll
      for (int s0 = 0; s0 < 128; s0 += 32) {
        bf16x8 paf[2];
#pragma unroll
        for (int rt = 0; rt < 2; ++rt)
          paf[rt] = *(const bf16x8*)&Ab[(w * 32 + rt * 16 + lrow) * ABS + s0 + quad * 8];
#pragma unroll
        for (int ct = 0; ct < 4; ++ct) {
          bf16x8 bv8 = *(const bf16x8*)&Vt[(ct * 16 + lrow) * ABS + s0 + quad * 8];
#pragma unroll
          for (int rt = 0; rt < 2; ++rt)
            pacc[rt][ct] = MFMA_BF16(paf[rt], bv8, pacc[rt][ct], 0, 0, 0);
        }
      }
#pragma unroll
      for (int rt = 0; rt < 2; ++rt)
#pragma unroll
        for (int ct = 0; ct < 4; ++ct)
#pragma unroll
          for (int r = 0; r < 4; ++r) {
            int row = w * 32 + rt * 16 + quad * 4 + r;
            Ob[(size_t)row * 256 + H0 + hc * 64 + ct * 16 + lrow] = pacc[rt][ct][r];
          }
      __syncthreads();
    }
  }
}

extern "C" void kernel_launch(void* const* d_in, const int* in_sizes, int n_in,
                              void* d_out, int out_size, void* d_ws, size_t ws_size,
                              hipStream_t stream) {
  const float* node  = (const float*)d_in[0];
  const float* neigh = (const float*)d_in[1];
  const float* Wq = (const float*)d_in[3];
  const float* Wk = (const float*)d_in[4];
  const float* Wv = (const float*)d_in[5];
  const float* Wb = (const float*)d_in[6];
  const float* bv = (const float*)d_in[7];

  float* out  = (float*)d_out;
  float* Aout = out + (size_t)64 * 17 * 128 * 256;

  size_t need = (size_t)(65536 + 65536 + 2097152) * 4 + (size_t)65536 * 2;
  if (ws_size < need) { fprintf(stderr, "ws too small: %zu < %zu\n", ws_size, need); return; }
  float* wsf = (float*)d_ws;
  float* Wc  = wsf;
  float* We  = wsf + 65536;
  float* qWk = wsf + 131072;
  bf16*  Wvb = (bf16*)(wsf + 131072 + 2097152);

  k_wvb<<<64, 256, 0, stream>>>(Wv, Wvb);
  k_wc<<<256, 256, 0, stream>>>(Wq, Wb, Wc);
  k_we<<<256, 256, 0, stream>>>(Wc, Wk, We);
  k_qwk<<<dim3(128, 4), 256, 0, stream>>>(node, We, qWk);
  k_fused<<<1088, 256, 0, stream>>>(qWk, node, neigh, bv, Wvb, Aout, out);
}

// Round 3
// 495.039 us; speedup vs baseline: 1.5925x; 1.5925x over previous
//
#include <hip/hip_runtime.h>
#include <cstdio>

// B=64, NN=17, T=128, H=256.
// d_out = outputs [64,17,128,256] fp32 ++ A [64,17,128,128] fp32.
//
// Refactor: We = Wq^T@Wb@Wk; qWk = node@We; S = qWk@kv^T + b[s]; A = softmax_s(S);
// out = A @ (kv@Wv^T).
// Round 2: QK^T via bf16 MFMA hi/lo split; softmax + PV fused.
// Round 3: V computed inside k_fused, LDS-staged -> latency-bound (40 barriers).
// Round 4: barrier-free V-gemm BUT partial-unroll pragmas made vacc runtime-
//   indexed -> scratch (rule #20): WRITE_SIZE 1.33GB, 2x regression.
// Round 5: same structure, all accumulator loops FULLY unrolled (vacc/pacc in
//   registers); phase-1 Q is also wave-private so Q fragments load straight
//   from global (no Q LDS staging at all) — K alone is staged+prefetched.

typedef __bf16 bf16;
typedef __attribute__((ext_vector_type(8))) __bf16 bf16x8;
typedef __attribute__((ext_vector_type(4))) __bf16 bf16x4;
typedef __attribute__((ext_vector_type(4))) float floatx4;

#define MFMA_BF16 __builtin_amdgcn_mfma_f32_16x16x32_bf16

__device__ __forceinline__ const float* kv_row_ptr(const float* node, const float* neigh, int bn, int s) {
  int b = bn / 17, nn = bn % 17;
  return (nn == 0) ? node + ((size_t)b * 128 + s) * 256
                   : neigh + (((size_t)b * 16 + (nn - 1)) * 128 + s) * 256;
}

// ---------- K0a: Wc = Wq^T @ Wb ----------
__global__ __launch_bounds__(256) void k_wc(const float* __restrict__ Wq, const float* __restrict__ Wb,
                                            float* __restrict__ Wc) {
  int m = blockIdx.x, h = threadIdx.x;
  float acc = 0.f;
  for (int k = 0; k < 256; ++k) acc = fmaf(Wq[k * 256 + m], Wb[k * 256 + h], acc);
  Wc[m * 256 + h] = acc;
}

// ---------- K0b: We = Wc @ Wk ----------
__global__ __launch_bounds__(256) void k_we(const float* __restrict__ Wc, const float* __restrict__ Wk,
                                            float* __restrict__ We) {
  int m = blockIdx.x, g = threadIdx.x;
  float acc = 0.f;
  for (int k = 0; k < 256; ++k) acc = fmaf(Wc[m * 256 + k], Wk[k * 256 + g], acc);
  We[m * 256 + g] = acc;
}

// ---------- K0c: Wvb = bf16(Wv) ----------
__global__ __launch_bounds__(256) void k_wvb(const float* __restrict__ Wv, bf16* __restrict__ Wvb) {
  int i = (blockIdx.x * 256 + threadIdx.x) * 4;
  float4 v = *(const float4*)(Wv + i);
  bf16x4 o;
  o[0] = (bf16)v.x; o[1] = (bf16)v.y; o[2] = (bf16)v.z; o[3] = (bf16)v.w;
  *(bf16x4*)(Wvb + i) = o;
}

// ---------- K1: qWk = node @ We; M=8192,N=256,K=256 fp32 ----------
__global__ __launch_bounds__(256) void k_qwk(const float* __restrict__ X, const float* __restrict__ W,
                                             float* __restrict__ Y) {
  __shared__ float As[32][64];
  __shared__ float Bs[32][64];
  int tid = threadIdx.x;
  int m0 = blockIdx.x * 64, n0 = blockIdx.y * 64;
  int tx = tid & 15, ty = tid >> 4;
  float acc[4][4] = {};
  int r = tid >> 3, c4 = (tid & 7) * 4;
  int kr = tid >> 4, c4b = (tid & 15) * 4;
  for (int k0 = 0; k0 < 256; k0 += 32) {
#pragma unroll
    for (int p = 0; p < 2; ++p) {
      float4 v = *(const float4*)(X + (size_t)(m0 + r + p * 32) * 256 + k0 + c4);
      As[c4 + 0][r + p * 32] = v.x; As[c4 + 1][r + p * 32] = v.y;
      As[c4 + 2][r + p * 32] = v.z; As[c4 + 3][r + p * 32] = v.w;
    }
#pragma unroll
    for (int p = 0; p < 2; ++p) {
      float4 v = *(const float4*)(W + (size_t)(k0 + kr + p * 16) * 256 + n0 + c4b);
      *(float4*)&Bs[kr + p * 16][c4b] = v;
    }
    __syncthreads();
#pragma unroll 8
    for (int k = 0; k < 32; ++k) {
      float a[4], bb[4];
#pragma unroll
      for (int i = 0; i < 4; ++i) a[i] = As[k][ty * 4 + i];
#pragma unroll
      for (int j = 0; j < 4; ++j) bb[j] = Bs[k][tx * 4 + j];
#pragma unroll
      for (int i = 0; i < 4; ++i)
#pragma unroll
        for (int j = 0; j < 4; ++j) acc[i][j] = fmaf(a[i], bb[j], acc[i][j]);
    }
    __syncthreads();
  }
#pragma unroll
  for (int i = 0; i < 4; ++i) {
    float4 v = make_float4(acc[i][0], acc[i][1], acc[i][2], acc[i][3]);
    *(float4*)(Y + (size_t)(m0 + ty * 4 + i) * 256 + n0 + tx * 4) = v;
  }
}

// ---------- K3 fused ----------
// one block per bn; 256 threads = 4 waves; wave w owns rows w*32..w*32+31.
#define QKS 40   // padded k-stride (bf16) for K staging buffers
#define ABS 136  // padded s-stride (bf16) for A / Vt buffers
__global__ __launch_bounds__(256) void k_fused(const float* __restrict__ qWk, const float* __restrict__ node,
                                               const float* __restrict__ neigh, const float* __restrict__ bvec,
                                               const bf16* __restrict__ Wvb,
                                               float* __restrict__ Aout, float* __restrict__ Out) {
  __shared__ __align__(16) char smem[52224];
  bf16* Khi = (bf16*)smem;               // [128][QKS] (phase 1)
  bf16* Klo = (bf16*)(smem + 10240);
  bf16* Ab  = (bf16*)smem;               // [128][ABS] (phase 2, aliases K bufs)
  bf16* Vt  = (bf16*)(smem + 34816);     // [64][ABS]  (phase 2)

  int tid = threadIdx.x;
  int w = tid >> 6, lane = tid & 63, lrow = lane & 15, quad = lane >> 4;
  int bn = blockIdx.x;
  const float* Q = qWk + (size_t)(bn / 17) * 128 * 256;
  const float* K = kv_row_ptr(node, neigh, bn, 0);

  int srow = tid >> 1;            // K staging row 0..127
  int skb = (tid & 1) * 16;       // K staging k base 0 or 16

  floatx4 acc[2][8];
#pragma unroll
  for (int rt = 0; rt < 2; ++rt)
#pragma unroll
    for (int ct = 0; ct < 8; ++ct) acc[rt][ct] = (floatx4)0.0f;

  // ---- phase 1: S = Q @ K^T via 3-term hi/lo split ----
  // K staged hi/lo in LDS (prefetched); Q rows are wave-private -> per-lane
  // fragments loaded straight from global, no Q staging.
  const float* kb = K + (size_t)srow * 256 + skb;
  const float* qlane = Q + (size_t)(w * 32 + lrow) * 256 + quad * 8;
  float4 pk[4];
#pragma unroll
  for (int j = 0; j < 4; ++j) pk[j] = *(const float4*)(kb + j * 4);

  for (int k0 = 0; k0 < 256; k0 += 32) {
#pragma unroll
    for (int half = 0; half < 2; ++half) {
      float kf[8] = {pk[half * 2].x, pk[half * 2].y, pk[half * 2].z, pk[half * 2].w,
                     pk[half * 2 + 1].x, pk[half * 2 + 1].y, pk[half * 2 + 1].z, pk[half * 2 + 1].w};
      bf16x8 kh, kl;
#pragma unroll
      for (int u = 0; u < 8; ++u) {
        bf16 h2 = (bf16)kf[u]; kh[u] = h2; kl[u] = (bf16)(kf[u] - (float)h2);
      }
      int off = srow * QKS + skb + half * 8;
      *(bf16x8*)&Khi[off] = kh; *(bf16x8*)&Klo[off] = kl;
    }
    if (k0 < 224) {  // prefetch next K k-step; latency spans barrier + MFMAs
#pragma unroll
      for (int j = 0; j < 4; ++j) pk[j] = *(const float4*)(kb + k0 + 32 + j * 4);
    }
    // Q fragments for this k-step (per-lane, global); consumed after barrier
    float4 q0[2], q1[2];
#pragma unroll
    for (int rt = 0; rt < 2; ++rt) {
      const float* qp = qlane + (size_t)rt * 16 * 256 + k0;
      q0[rt] = *(const float4*)qp;
      q1[rt] = *(const float4*)(qp + 4);
    }
    __syncthreads();
    bf16x8 ah[2], al[2];
#pragma unroll
    for (int rt = 0; rt < 2; ++rt) {
      float qf[8] = {q0[rt].x, q0[rt].y, q0[rt].z, q0[rt].w,
                     q1[rt].x, q1[rt].y, q1[rt].z, q1[rt].w};
#pragma unroll
      for (int u = 0; u < 8; ++u) {
        bf16 h = (bf16)qf[u]; ah[rt][u] = h; al[rt][u] = (bf16)(qf[u] - (float)h);
      }
    }
#pragma unroll
    for (int ct = 0; ct < 8; ++ct) {
      int off = (ct * 16 + lrow) * QKS + quad * 8;
      bf16x8 bh = *(const bf16x8*)&Khi[off];
      bf16x8 bl = *(const bf16x8*)&Klo[off];
#pragma unroll
      for (int rt = 0; rt < 2; ++rt) {
        acc[rt][ct] = MFMA_BF16(ah[rt], bh, acc[rt][ct], 0, 0, 0);
        acc[rt][ct] = MFMA_BF16(al[rt], bh, acc[rt][ct], 0, 0, 0);
        acc[rt][ct] = MFMA_BF16(ah[rt], bl, acc[rt][ct], 0, 0, 0);
      }
    }
    __syncthreads();
  }

  // ---- softmax over s (per row), in registers ----
  float bvv[8];
#pragma unroll
  for (int ct = 0; ct < 8; ++ct) bvv[ct] = bvec[ct * 16 + lrow];
#pragma unroll
  for (int rt = 0; rt < 2; ++rt)
#pragma unroll
    for (int r = 0; r < 4; ++r) {
      float mx = -3.402823466e+38f;
#pragma unroll
      for (int ct = 0; ct < 8; ++ct) {
        float v = acc[rt][ct][r] + bvv[ct];
        acc[rt][ct][r] = v;
        mx = fmaxf(mx, v);
      }
#pragma unroll
      for (int off = 1; off < 16; off <<= 1) mx = fmaxf(mx, __shfl_xor(mx, off, 64));
      float s = 0.f;
#pragma unroll
      for (int ct = 0; ct < 8; ++ct) {
        float e = __expf(acc[rt][ct][r] - mx);
        acc[rt][ct][r] = e;
        s += e;
      }
#pragma unroll
      for (int off = 1; off < 16; off <<= 1) s += __shfl_xor(s, off, 64);
      float inv = 1.f / s;
#pragma unroll
      for (int ct = 0; ct < 8; ++ct) acc[rt][ct][r] *= inv;
    }

  // ---- write A (global fp32) + Ab (LDS bf16; rows w*32.. are wave-private) ----
  float* Ag = Aout + (size_t)bn * 128 * 128;
#pragma unroll
  for (int rt = 0; rt < 2; ++rt)
#pragma unroll
    for (int r = 0; r < 4; ++r) {
      int row = w * 32 + rt * 16 + quad * 4 + r;
#pragma unroll
      for (int ct = 0; ct < 8; ++ct) {
        int s = ct * 16 + lrow;
        float v = acc[rt][ct][r];
        Ag[(size_t)row * 128 + s] = v;
        Ab[row * ABS + s] = (bf16)v;
      }
    }

  // ---- phase 2: per 128-h half — barrier-free per-wave V-gemm (kv direct
  //      from L2/L3), then per 64-h chunk: Vt transpose + PV ----
  // ALL loops indexing vacc/pacc are fully unrolled (rule #20).
  float* Ob = Out + (size_t)bn * 128 * 256;
  for (int hh = 0; hh < 2; ++hh) {
    const int H0 = hh * 128;
    floatx4 vacc[2][8];
#pragma unroll
    for (int rt = 0; rt < 2; ++rt)
#pragma unroll
      for (int ct = 0; ct < 8; ++ct) vacc[rt][ct] = (floatx4)0.0f;

#pragma unroll
    for (int kk = 0; kk < 8; ++kk) {  // k = kk*32
      bf16x8 af[2];
#pragma unroll
      for (int rt = 0; rt < 2; ++rt) {
        const float* kp = K + (size_t)(w * 32 + rt * 16 + lrow) * 256 + kk * 32 + quad * 8;
        float4 a = *(const float4*)kp, b2 = *(const float4*)(kp + 4);
        bf16x8 o;
        o[0] = (bf16)a.x;  o[1] = (bf16)a.y;  o[2] = (bf16)a.z;  o[3] = (bf16)a.w;
        o[4] = (bf16)b2.x; o[5] = (bf16)b2.y; o[6] = (bf16)b2.z; o[7] = (bf16)b2.w;
        af[rt] = o;
      }
#pragma unroll
      for (int ct = 0; ct < 8; ++ct) {
        bf16x8 bwv = *(const bf16x8*)&Wvb[(size_t)(H0 + ct * 16 + lrow) * 256 + kk * 32 + quad * 8];
#pragma unroll
        for (int rt = 0; rt < 2; ++rt)
          vacc[rt][ct] = MFMA_BF16(af[rt], bwv, vacc[rt][ct], 0, 0, 0);
      }
    }

    // two 64-h chunks: transpose V through LDS, then PV
#pragma unroll
    for (int hc = 0; hc < 2; ++hc) {
#pragma unroll
      for (int ct = 0; ct < 4; ++ct)
#pragma unroll
        for (int rt = 0; rt < 2; ++rt) {
          bf16x4 o;
#pragma unroll
          for (int r = 0; r < 4; ++r) o[r] = (bf16)vacc[rt][hc * 4 + ct][r];
          *(bf16x4*)&Vt[(ct * 16 + lrow) * ABS + w * 32 + rt * 16 + quad * 4] = o;
        }
      __syncthreads();
      floatx4 pacc[2][4];
#pragma unroll
      for (int rt = 0; rt < 2; ++rt)
#pragma unroll
        for (int ct = 0; ct < 4; ++ct) pacc[rt][ct] = (floatx4)0.0f;
#pragma unroll
      for (int s0 = 0; s0 < 128; s0 += 32) {
        bf16x8 paf[2];
#pragma unroll
        for (int rt = 0; rt < 2; ++rt)
          paf[rt] = *(const bf16x8*)&Ab[(w * 32 + rt * 16 + lrow) * ABS + s0 + quad * 8];
#pragma unroll
        for (int ct = 0; ct < 4; ++ct) {
          bf16x8 bv8 = *(const bf16x8*)&Vt[(ct * 16 + lrow) * ABS + s0 + quad * 8];
#pragma unroll
          for (int rt = 0; rt < 2; ++rt)
            pacc[rt][ct] = MFMA_BF16(paf[rt], bv8, pacc[rt][ct], 0, 0, 0);
        }
      }
#pragma unroll
      for (int rt = 0; rt < 2; ++rt)
#pragma unroll
        for (int ct = 0; ct < 4; ++ct)
#pragma unroll
          for (int r = 0; r < 4; ++r) {
            int row = w * 32 + rt * 16 + quad * 4 + r;
            Ob[(size_t)row * 256 + H0 + hc * 64 + ct * 16 + lrow] = pacc[rt][ct][r];
          }
      __syncthreads();
    }
  }
}

extern "C" void kernel_launch(void* const* d_in, const int* in_sizes, int n_in,
                              void* d_out, int out_size, void* d_ws, size_t ws_size,
                              hipStream_t stream) {
  const float* node  = (const float*)d_in[0];
  const float* neigh = (const float*)d_in[1];
  const float* Wq = (const float*)d_in[3];
  const float* Wk = (const float*)d_in[4];
  const float* Wv = (const float*)d_in[5];
  const float* Wb = (const float*)d_in[6];
  const float* bv = (const float*)d_in[7];

  float* out  = (float*)d_out;
  float* Aout = out + (size_t)64 * 17 * 128 * 256;

  size_t need = (size_t)(65536 + 65536 + 2097152) * 4 + (size_t)65536 * 2;
  if (ws_size < need) { fprintf(stderr, "ws too small: %zu < %zu\n", ws_size, need); return; }
  float* wsf = (float*)d_ws;
  float* Wc  = wsf;
  float* We  = wsf + 65536;
  float* qWk = wsf + 131072;
  bf16*  Wvb = (bf16*)(wsf + 131072 + 2097152);

  k_wvb<<<64, 256, 0, stream>>>(Wv, Wvb);
  k_wc<<<256, 256, 0, stream>>>(Wq, Wb, Wc);
  k_we<<<256, 256, 0, stream>>>(Wc, Wk, We);
  k_qwk<<<dim3(128, 4), 256, 0, stream>>>(node, We, qWk);
  k_fused<<<1088, 256, 0, stream>>>(qWk, node, neigh, bv, Wvb, Aout, out);
}